// Round 6
// baseline (269.335 us; speedup 1.0000x reference)
//
#include <hip/hip_runtime.h>

#define EPSV 1e-5f

typedef float f32x2 __attribute__((ext_vector_type(2)));

// ---------- fused stage-1 stats: blocks [0,1024) reduce y, [1024,1280) reduce x ----------
__global__ __launch_bounds__(256) void stats_kernel(const float* __restrict__ y,
                                                    const float* __restrict__ x,
                                                    float* __restrict__ part) {
    int bid = blockIdx.x;
    const float* src = (bid < 1024) ? (y + (size_t)bid * 16384)
                                    : (x + (size_t)(bid - 1024) * 16384);
    const float4* p = (const float4*)src;
    float s = 0.f, ss = 0.f;
    #pragma unroll 8
    for (int i = threadIdx.x; i < 4096; i += 256) {
        float4 v = p[i];
        s  += v.x + v.y + v.z + v.w;
        ss += v.x*v.x + v.y*v.y + v.z*v.z + v.w*v.w;
    }
    for (int off = 32; off > 0; off >>= 1) {
        s  += __shfl_down(s, off);
        ss += __shfl_down(ss, off);
    }
    __shared__ float red[8];
    int wid = threadIdx.x >> 6, lane = threadIdx.x & 63;
    if (lane == 0) { red[wid*2] = s; red[wid*2+1] = ss; }
    __syncthreads();
    if (threadIdx.x == 0) {
        part[bid*2+0] = red[0] + red[2] + red[4] + red[6];
        part[bid*2+1] = red[1] + red[3] + red[5] + red[7];
    }
}

// ---------- fused make_eff: blocks [0,128) Q-side, [128,256) K-side ----------
__global__ __launch_bounds__(64) void make_eff_kernel(const float* __restrict__ qw, const float* __restrict__ qb,
                                                      const float* __restrict__ gyw, const float* __restrict__ gyb,
                                                      const float* __restrict__ kw, const float* __restrict__ kb,
                                                      const float* __restrict__ gxw, const float* __restrict__ gxb,
                                                      const float* __restrict__ part,
                                                      float* __restrict__ WeffQ, float* __restrict__ beffQ,
                                                      float* __restrict__ WeffK, float* __restrict__ beffK) {
    int id = blockIdx.x;
    int isK = id >> 7, b = (id >> 5) & 3, e = id & 31;
    const float* w     = isK ? kw  : qw;
    const float* bias  = isK ? kb  : qb;
    const float* gamma = isK ? gxw : gyw;
    const float* beta  = isK ? gxb : gyb;
    float inv_n = isK ? (1.f/32768.f) : (1.f/131072.f);
    float* W  = isK ? WeffK : WeffQ;
    float* be = isK ? beffK : beffQ;
    float partial = 0.f;
    for (int c = threadIdx.x; c < 256; c += 64) {
        int g = c >> 3, grp = b*32 + g;
        float s = 0.f, ss = 0.f;
        if (isK) {
            #pragma unroll
            for (int k2 = 0; k2 < 2; ++k2) {
                s  += part[(1024 + grp*2 + k2)*2 + 0];
                ss += part[(1024 + grp*2 + k2)*2 + 1];
            }
        } else {
            #pragma unroll
            for (int k2 = 0; k2 < 8; ++k2) {
                s  += part[(grp*8 + k2)*2 + 0];
                ss += part[(grp*8 + k2)*2 + 1];
            }
        }
        float mu = s * inv_n;
        float rs = rsqrtf(fmaf(-mu, mu, ss * inv_n) + EPSV);
        float wc = w[e*256 + c];
        float weff = wc * gamma[c] * rs;
        W[((size_t)b*256 + c)*32 + e] = weff;
        partial += wc * beta[c] - weff * mu;
    }
    for (int off = 32; off > 0; off >>= 1) partial += __shfl_down(partial, off);
    if (threadIdx.x == 0) be[b*32 + e] = partial + bias[e];
}

// ---------- fused 1x1 projection, flat 640-block grid, packed fp32 ----------
__global__ __launch_bounds__(256) void proj_kernel(const float* __restrict__ y, const float* __restrict__ x,
                                                   const float* __restrict__ WeffQ, const float* __restrict__ beffQ,
                                                   const float* __restrict__ WeffK, const float* __restrict__ beffK,
                                                   float* __restrict__ qbuf, float* __restrict__ kbuf) {
    int bid = blockIdx.x;
    int isX = bid >= 512;
    int lb = isX ? bid - 512 : bid;
    int b    = isX ? (lb >> 5) : (lb >> 7);
    int pxb  = isX ? (lb & 31) : (lb & 127);
    int npix = isX ? 4096 : 16384;
    const float* src   = isX ? x : y;
    const float* WeffT = isX ? WeffK : WeffQ;
    const float* beff  = isX ? beffK : beffQ;
    float* dst = isX ? kbuf : qbuf;

    int pix0 = pxb * 128 + (threadIdx.x & 63) * 2;
    int eg = __builtin_amdgcn_readfirstlane(threadIdx.x >> 6);
    const float* wp = WeffT + (size_t)b*256*32 + eg*8;
    f32x2 acc[8];   // (px0, px1) per e
    #pragma unroll
    for (int j = 0; j < 8; ++j) {
        float bv = beff[b*32 + eg*8 + j];
        acc[j] = (f32x2){bv, bv};
    }
    const float* ysrc = src + (size_t)b*256*npix + pix0;
    #pragma unroll 8
    for (int c = 0; c < 256; ++c) {
        f32x2 t = *(const f32x2*)(ysrc + (size_t)c*npix);
        #pragma unroll
        for (int j = 0; j < 8; ++j)
            acc[j] += t * wp[c*32 + j];   // scalar splat -> v_pk_fma_f32
    }
    float* dbase = dst + ((size_t)b*npix + pix0)*32 + eg*8;
    #pragma unroll
    for (int px = 0; px < 2; ++px) {
        float4 o0 = {acc[0][px], acc[1][px], acc[2][px], acc[3][px]};
        float4 o1 = {acc[4][px], acc[5][px], acc[6][px], acc[7][px]};
        *(float4*)(dbase + px*32 + 0) = o0;
        *(float4*)(dbase + px*32 + 4) = o1;
    }
}

// ---------- fused attention + gather ----------
// grid (8,8,8): bz = b*2 + half(128 ch). Block = 8x8 low-res tile.
// Phase 1 (thread = child, tid = 32h+16u+2w+v): 25 logits + softmax in regs,
//   store to pair-major sA: addr = (tid>>1)*54 + 2j + (tid&1)  (2-way banks = free).
// Phase 2 (thread = parent p=tid&63 x chgroup ci=tid>>6): pull 4 children's
//   weights as b64 pairs; gather with ONE b128 per (tap, 4ch) serving 4 children.
//   sX stride 20: b128 reads hit the 8-words/bank floor (banks 4k-periodic).
__global__ __launch_bounds__(256, 2) void attn_gather_kernel(const float* __restrict__ q,   // [B][16384][32]
                                                             const float* __restrict__ kk,  // [B][4096][32]
                                                             const float* __restrict__ x,   // [B][256][64][64]
                                                             float* __restrict__ out)       // [B][256][128][128]
{
    __shared__ __align__(16) float sPool[5184];  // k: [144 pos][36]; reused as x: [144 pos][20]
    __shared__ __align__(16) float sA[6912];     // 128 child-pairs * 54
    int h0 = blockIdx.y * 8, w0 = blockIdx.x * 8;
    int b = blockIdx.z >> 1, half = blockIdx.z & 1;
    int tid = threadIdx.x;

    // ---- stage k halo: pos-major, stride 36 ----
    for (int i = tid; i < 1152; i += 256) {
        int pos = i >> 3, e4 = i & 7;
        int r = pos / 12, c = pos - 12*r;
        int gh = h0 + r - 2, gw = w0 + c - 2;
        float4 v = make_float4(0.f, 0.f, 0.f, 0.f);
        if (gh >= 0 && gh < 64 && gw >= 0 && gw < 64)
            v = *(const float4*)(kk + (((size_t)b*4096 + gh*64 + gw)*32 + e4*4));
        *(float4*)&sPool[pos*36 + e4*4] = v;
    }

    int h = tid >> 5, u = (tid >> 4) & 1, w = (tid >> 1) & 7, v = tid & 1;

    // ---- this child's q (16 pairs) ----
    f32x2 qv[16];
    {
        int hh = 2*(h0 + h) + u, ww = 2*(w0 + w) + v;
        const f32x2* qp = (const f32x2*)(q + (((size_t)b*16384 + hh*128 + ww)*32));
        #pragma unroll
        for (int i2 = 0; i2 < 16; ++i2) qv[i2] = qp[i2];
    }
    __syncthreads();

    // ---- 25 logits (packed dot) + in-register softmax ----
    float a[25];
    const float* kbase = &sPool[(h*12 + w)*36];
    #pragma unroll
    for (int j = 0; j < 25; ++j) {
        int dy = j / 5, dx = j - 5*dy;
        const f32x2* kp = (const f32x2*)(kbase + (dy*12 + dx)*36);
        f32x2 acc2 = {0.f, 0.f};
        #pragma unroll
        for (int e2 = 0; e2 < 16; ++e2) acc2 += qv[e2] * kp[e2];
        a[j] = acc2.x + acc2.y;
    }
    {
        float m = -1e30f;
        #pragma unroll
        for (int j = 0; j < 25; ++j) m = fmaxf(m, a[j]);
        float s = 0.f;
        #pragma unroll
        for (int j = 0; j < 25; ++j) { a[j] = __expf(a[j] - m); s += a[j]; }
        float inv = 1.f / s;
        int abase = (tid >> 1)*54 + (tid & 1);
        #pragma unroll
        for (int j = 0; j < 25; ++j) sA[abase + 2*j] = a[j] * inv;
    }
    __syncthreads();

    // ---- re-role: parent + channel group; pull children's weights (b64) ----
    int p = tid & 63, ci = tid >> 6;
    int pw = p & 7, ph = p >> 3;
    float a4[4][25];
    #pragma unroll
    for (int uu = 0; uu < 2; ++uu) {
        int pairbase = (16*ph + 8*uu + pw) * 54;
        #pragma unroll
        for (int j = 0; j < 25; ++j) {
            f32x2 av = *(const f32x2*)&sA[pairbase + 2*j];
            a4[uu*2+0][j] = av.x;
            a4[uu*2+1][j] = av.y;
        }
    }

    // ---- gather: 8 chunks x 16 ch; thread covers 4 children x 4 ch per chunk ----
    int cc0 = ci * 4;
    for (int c0 = 0; c0 < 128; c0 += 16) {
        if (c0) __syncthreads();
        for (int i = 0; i < 9; ++i) {          // 2304 = 16 ch * 144 pos
            int t = i*256 + tid;
            int cc = t / 144, pos = t - 144*cc;
            int r = pos / 12, cl = pos - 12*r;
            int gh = h0 + r - 2, gw = w0 + cl - 2;
            float val = 0.f;
            if (gh >= 0 && gh < 64 && gw >= 0 && gw < 64)
                val = x[(((size_t)b*256 + half*128 + c0 + cc)*64 + gh)*64 + gw];
            sPool[pos*20 + cc] = val;
        }
        __syncthreads();

        f32x2 acc01[4], acc23[4];
        #pragma unroll
        for (int uv = 0; uv < 4; ++uv) {
            acc01[uv] = (f32x2){0.f, 0.f};
            acc23[uv] = (f32x2){0.f, 0.f};
        }
        #pragma unroll
        for (int j = 0; j < 25; ++j) {
            int dy = j / 5, dx = j - 5*dy;
            int pos = (ph+dy)*12 + (pw+dx);
            float4 xv = *(const float4*)&sPool[pos*20 + cc0];
            f32x2 x01 = {xv.x, xv.y}, x23 = {xv.z, xv.w};
            #pragma unroll
            for (int uv = 0; uv < 4; ++uv) {
                float aw = a4[uv][j];
                acc01[uv] += x01 * aw;
                acc23[uv] += x23 * aw;
            }
        }
        int cbase = half*128 + c0 + cc0;
        #pragma unroll
        for (int u2 = 0; u2 < 2; ++u2) {
            int hh2 = 2*(h0+ph) + u2, ww2 = 2*(w0+pw);
            #pragma unroll
            for (int t = 0; t < 4; ++t) {
                float v0 = (t < 2) ? acc01[u2*2+0][t & 1] : acc23[u2*2+0][t & 1];
                float v1 = (t < 2) ? acc01[u2*2+1][t & 1] : acc23[u2*2+1][t & 1];
                size_t ob = (((size_t)b*256 + cbase + t)*128 + hh2)*128 + ww2;
                *(float2*)(out + ob) = make_float2(v0, v1);
            }
        }
    }
}

extern "C" void kernel_launch(void* const* d_in, const int* in_sizes, int n_in,
                              void* d_out, int out_size, void* d_ws, size_t ws_size,
                              hipStream_t stream) {
    const float* y   = (const float*)d_in[0];
    const float* x   = (const float*)d_in[1];
    const float* gyw = (const float*)d_in[2];
    const float* gyb = (const float*)d_in[3];
    const float* gxw = (const float*)d_in[4];
    const float* gxb = (const float*)d_in[5];
    const float* qw  = (const float*)d_in[6];
    const float* qb  = (const float*)d_in[7];
    const float* kw  = (const float*)d_in[8];
    const float* kb  = (const float*)d_in[9];
    float* out = (float*)d_out;
    float* ws  = (float*)d_ws;

    float* part  = ws;              // 2560
    float* WeffQ = ws + 2560;       // 32768
    float* beffQ = ws + 35328;      // 128
    float* WeffK = ws + 35456;      // 32768
    float* beffK = ws + 68224;      // 128
    float* qbuf  = ws + 68352;      // 4*16384*32 = 2097152
    float* kbuf  = ws + 2165504;    // 4*4096*32  = 524288

    stats_kernel<<<1280, 256, 0, stream>>>(y, x, part);
    make_eff_kernel<<<256, 64, 0, stream>>>(qw, qb, gyw, gyb, kw, kb, gxw, gxb,
                                            part, WeffQ, beffQ, WeffK, beffK);
    proj_kernel<<<640, 256, 0, stream>>>(y, x, WeffQ, beffQ, WeffK, beffK, qbuf, kbuf);
    attn_gather_kernel<<<dim3(8, 8, 8), 256, 0, stream>>>(qbuf, kbuf, x, out);
}

// Round 7
// 260.012 us; speedup vs baseline: 1.0359x; 1.0359x over previous
//
#include <hip/hip_runtime.h>

#define EPSV 1e-5f

typedef float f32x2 __attribute__((ext_vector_type(2)));

// ---------- fused stage-1 stats: blocks [0,1024) reduce y, [1024,1280) reduce x ----------
__global__ __launch_bounds__(256) void stats_kernel(const float* __restrict__ y,
                                                    const float* __restrict__ x,
                                                    float* __restrict__ part) {
    int bid = blockIdx.x;
    const float* src = (bid < 1024) ? (y + (size_t)bid * 16384)
                                    : (x + (size_t)(bid - 1024) * 16384);
    const float4* p = (const float4*)src;
    float s = 0.f, ss = 0.f;
    #pragma unroll 8
    for (int i = threadIdx.x; i < 4096; i += 256) {
        float4 v = p[i];
        s  += v.x + v.y + v.z + v.w;
        ss += v.x*v.x + v.y*v.y + v.z*v.z + v.w*v.w;
    }
    for (int off = 32; off > 0; off >>= 1) {
        s  += __shfl_down(s, off);
        ss += __shfl_down(ss, off);
    }
    __shared__ float red[8];
    int wid = threadIdx.x >> 6, lane = threadIdx.x & 63;
    if (lane == 0) { red[wid*2] = s; red[wid*2+1] = ss; }
    __syncthreads();
    if (threadIdx.x == 0) {
        part[bid*2+0] = red[0] + red[2] + red[4] + red[6];
        part[bid*2+1] = red[1] + red[3] + red[5] + red[7];
    }
}

// ---------- fused make_eff: blocks [0,128) Q-side, [128,256) K-side ----------
__global__ __launch_bounds__(64) void make_eff_kernel(const float* __restrict__ qw, const float* __restrict__ qb,
                                                      const float* __restrict__ gyw, const float* __restrict__ gyb,
                                                      const float* __restrict__ kw, const float* __restrict__ kb,
                                                      const float* __restrict__ gxw, const float* __restrict__ gxb,
                                                      const float* __restrict__ part,
                                                      float* __restrict__ WeffQ, float* __restrict__ beffQ,
                                                      float* __restrict__ WeffK, float* __restrict__ beffK) {
    int id = blockIdx.x;
    int isK = id >> 7, b = (id >> 5) & 3, e = id & 31;
    const float* w     = isK ? kw  : qw;
    const float* bias  = isK ? kb  : qb;
    const float* gamma = isK ? gxw : gyw;
    const float* beta  = isK ? gxb : gyb;
    float inv_n = isK ? (1.f/32768.f) : (1.f/131072.f);
    float* W  = isK ? WeffK : WeffQ;
    float* be = isK ? beffK : beffQ;
    float partial = 0.f;
    for (int c = threadIdx.x; c < 256; c += 64) {
        int g = c >> 3, grp = b*32 + g;
        float s = 0.f, ss = 0.f;
        if (isK) {
            #pragma unroll
            for (int k2 = 0; k2 < 2; ++k2) {
                s  += part[(1024 + grp*2 + k2)*2 + 0];
                ss += part[(1024 + grp*2 + k2)*2 + 1];
            }
        } else {
            #pragma unroll
            for (int k2 = 0; k2 < 8; ++k2) {
                s  += part[(grp*8 + k2)*2 + 0];
                ss += part[(grp*8 + k2)*2 + 1];
            }
        }
        float mu = s * inv_n;
        float rs = rsqrtf(fmaf(-mu, mu, ss * inv_n) + EPSV);
        float wc = w[e*256 + c];
        float weff = wc * gamma[c] * rs;
        W[((size_t)b*256 + c)*32 + e] = weff;
        partial += wc * beta[c] - weff * mu;
    }
    for (int off = 32; off > 0; off >>= 1) partial += __shfl_down(partial, off);
    if (threadIdx.x == 0) be[b*32 + e] = partial + bias[e];
}

// ---------- fused 1x1 projection, flat 640-block grid, packed fp32 ----------
__global__ __launch_bounds__(256) void proj_kernel(const float* __restrict__ y, const float* __restrict__ x,
                                                   const float* __restrict__ WeffQ, const float* __restrict__ beffQ,
                                                   const float* __restrict__ WeffK, const float* __restrict__ beffK,
                                                   float* __restrict__ qbuf, float* __restrict__ kbuf) {
    int bid = blockIdx.x;
    int isX = bid >= 512;
    int lb = isX ? bid - 512 : bid;
    int b    = isX ? (lb >> 5) : (lb >> 7);
    int pxb  = isX ? (lb & 31) : (lb & 127);
    int npix = isX ? 4096 : 16384;
    const float* src   = isX ? x : y;
    const float* WeffT = isX ? WeffK : WeffQ;
    const float* beff  = isX ? beffK : beffQ;
    float* dst = isX ? kbuf : qbuf;

    int pix0 = pxb * 128 + (threadIdx.x & 63) * 2;
    int eg = __builtin_amdgcn_readfirstlane(threadIdx.x >> 6);
    const float* wp = WeffT + (size_t)b*256*32 + eg*8;
    f32x2 acc[8];
    #pragma unroll
    for (int j = 0; j < 8; ++j) {
        float bv = beff[b*32 + eg*8 + j];
        acc[j] = (f32x2){bv, bv};
    }
    const float* ysrc = src + (size_t)b*256*npix + pix0;
    #pragma unroll 8
    for (int c = 0; c < 256; ++c) {
        f32x2 t = *(const f32x2*)(ysrc + (size_t)c*npix);
        #pragma unroll
        for (int j = 0; j < 8; ++j)
            acc[j] += t * wp[c*32 + j];
    }
    float* dbase = dst + ((size_t)b*npix + pix0)*32 + eg*8;
    #pragma unroll
    for (int px = 0; px < 2; ++px) {
        float4 o0 = {acc[0][px], acc[1][px], acc[2][px], acc[3][px]};
        float4 o1 = {acc[4][px], acc[5][px], acc[6][px], acc[7][px]};
        *(float4*)(dbase + px*32 + 0) = o0;
        *(float4*)(dbase + px*32 + 4) = o1;
    }
}

// ---------- kernel A: attention weights, 512 threads ----------
// thread = (child cid = tid&255, tap-half = tid>>8). Logits into sA[child][28],
// softmax by threads <256, bounce to global [b][tile][child][28] (float4 rows).
__global__ __launch_bounds__(512) void attn_weights_kernel(const float* __restrict__ q,   // [B][16384][32]
                                                           const float* __restrict__ kk,  // [B][4096][32]
                                                           float* __restrict__ g_attn)    // [B][64][256*28]
{
    __shared__ __align__(16) float sK[5184];   // [144 pos][36]
    __shared__ __align__(16) float sA[7168];   // [256 child][28]
    int h0 = blockIdx.y * 8, w0 = blockIdx.x * 8;
    int b = blockIdx.z;
    int tid = threadIdx.x;

    // stage k halo: pos-major, stride 36
    for (int i = tid; i < 1152; i += 512) {
        int pos = i >> 3, e4 = i & 7;
        int r = pos / 12, c = pos - 12*r;
        int gh = h0 + r - 2, gw = w0 + c - 2;
        float4 v = make_float4(0.f, 0.f, 0.f, 0.f);
        if (gh >= 0 && gh < 64 && gw >= 0 && gw < 64)
            v = *(const float4*)(kk + (((size_t)b*4096 + gh*64 + gw)*32 + e4*4));
        *(float4*)&sK[pos*36 + e4*4] = v;
    }

    int cid = tid & 255, half = tid >> 8;
    int h = cid >> 5, u = (cid >> 4) & 1, w = (cid >> 1) & 7, v = cid & 1;

    float qv[32];
    {
        int hh = 2*(h0 + h) + u, ww = 2*(w0 + w) + v;
        const float4* qp = (const float4*)(q + (((size_t)b*16384 + hh*128 + ww)*32));
        #pragma unroll
        for (int i4 = 0; i4 < 8; ++i4) {
            float4 t = qp[i4];
            qv[i4*4+0]=t.x; qv[i4*4+1]=t.y; qv[i4*4+2]=t.z; qv[i4*4+3]=t.w;
        }
    }
    __syncthreads();

    // 13 (half 0) or 12 (half 1) logits
    int jlo = half ? 13 : 0;
    int jhi = half ? 25 : 13;
    const float* kbase = &sK[(h*12 + w)*36];
    for (int j = jlo; j < jhi; ++j) {
        int dy = j / 5, dx = j - 5*dy;
        const float4* kp = (const float4*)(kbase + (dy*12 + dx)*36);
        float acc = 0.f;
        #pragma unroll
        for (int e4 = 0; e4 < 8; ++e4) {
            float4 kv = kp[e4];
            acc = fmaf(qv[e4*4+0], kv.x, acc);
            acc = fmaf(qv[e4*4+1], kv.y, acc);
            acc = fmaf(qv[e4*4+2], kv.z, acc);
            acc = fmaf(qv[e4*4+3], kv.w, acc);
        }
        sA[cid*28 + j] = acc;
    }
    __syncthreads();

    if (tid < 256) {
        float a[25], m = -1e30f;
        #pragma unroll
        for (int j = 0; j < 25; ++j) { a[j] = sA[tid*28 + j]; m = fmaxf(m, a[j]); }
        float s = 0.f;
        #pragma unroll
        for (int j = 0; j < 25; ++j) { a[j] = __expf(a[j] - m); s += a[j]; }
        float inv = 1.f / s;
        #pragma unroll
        for (int j = 0; j < 25; ++j) sA[tid*28 + j] = a[j] * inv;
        sA[tid*28 + 25] = 0.f; sA[tid*28 + 26] = 0.f; sA[tid*28 + 27] = 0.f;
    }
    __syncthreads();

    float4* gdst = (float4*)(g_attn + ((size_t)b*64 + blockIdx.y*8 + blockIdx.x)*7168);
    const float4* ssrc = (const float4*)sA;
    for (int i = tid; i < 1792; i += 512) gdst[i] = ssrc[i];
}

// ---------- kernel B: weighted gather, pair-threading ----------
// grid (8,8,16): bz = b*4 + slab(64 ch). 256 thr = 64 parents x 4 ch-quads.
// Full slab staged once: sX[144 pos][68] (39 KB, 4 blocks/CU), ONE barrier,
// then u-outer loop: a2[2][25] pulled from global (f4 rows), 25 b128 per
// (u, 16ch-chunk) each serving 2 children x 4 ch.
__global__ __launch_bounds__(256) void gather_kernel(const float* __restrict__ g_attn, // [B][64][256*28]
                                                     const float* __restrict__ x,      // [B][256][64][64]
                                                     float* __restrict__ out)          // [B][256][128][128]
{
    __shared__ __align__(16) float sX[9792];   // [144 pos][68]
    int h0 = blockIdx.y * 8, w0 = blockIdx.x * 8;
    int b = blockIdx.z >> 2, slab = blockIdx.z & 3;
    int tid = threadIdx.x;

    // stage 64 ch x 144 pos (zero-padded halo)
    #pragma unroll 4
    for (int i = 0; i < 36; ++i) {
        int t = i*256 + tid;
        int cc = t / 144, pos = t - 144*cc;
        int r = pos / 12, cl = pos - 12*r;
        int gh = h0 + r - 2, gw = w0 + cl - 2;
        float val = 0.f;
        if (gh >= 0 && gh < 64 && gw >= 0 && gw < 64)
            val = x[(((size_t)b*256 + slab*64 + cc)*64 + gh)*64 + gw];
        sX[pos*68 + cc] = val;
    }
    __syncthreads();

    int p = tid & 63, ci = tid >> 6;
    int pw = p & 7, ph = p >> 3;
    const float* tbase = g_attn + ((size_t)b*64 + blockIdx.y*8 + blockIdx.x)*7168;
    const float* xb0 = &sX[(ph*12 + pw)*68];
    int ww = 2*(w0 + pw);

    #pragma unroll
    for (int u = 0; u < 2; ++u) {
        // pull attn weights of the 2 children (v=0,1) of this parent at row u
        float a2[2][25];
        #pragma unroll
        for (int v = 0; v < 2; ++v) {
            const float4* ap = (const float4*)(tbase + (32*ph + 16*u + 2*pw + v)*28);
            float tmp[28];
            #pragma unroll
            for (int q4 = 0; q4 < 7; ++q4) *(float4*)&tmp[q4*4] = ap[q4];
            #pragma unroll
            for (int j = 0; j < 25; ++j) a2[v][j] = tmp[j];
        }
        int hh = 2*(h0 + ph) + u;

        #pragma unroll
        for (int c0i = 0; c0i < 4; ++c0i) {
            int cc = c0i*16 + ci*4;
            const float* xb = xb0 + cc;
            f32x2 acc00 = {0.f,0.f}, acc01 = {0.f,0.f};   // child v=0: ch{0,1},{2,3}
            f32x2 acc10 = {0.f,0.f}, acc11 = {0.f,0.f};   // child v=1
            #pragma unroll
            for (int j = 0; j < 25; ++j) {
                int dy = j / 5, dx = j - 5*dy;
                float4 xv = *(const float4*)(xb + (dy*12 + dx)*68);
                f32x2 x01 = {xv.x, xv.y}, x23 = {xv.z, xv.w};
                acc00 += x01 * a2[0][j];
                acc01 += x23 * a2[0][j];
                acc10 += x01 * a2[1][j];
                acc11 += x23 * a2[1][j];
            }
            int c = slab*64 + cc;
            size_t ob = (((size_t)b*256 + c)*128 + hh)*128 + ww;
            *(float2*)(out + ob)           = make_float2(acc00.x, acc10.x);
            *(float2*)(out + ob + 16384)   = make_float2(acc00.y, acc10.y);
            *(float2*)(out + ob + 32768)   = make_float2(acc01.x, acc11.x);
            *(float2*)(out + ob + 49152)   = make_float2(acc01.y, acc11.y);
        }
    }
}

extern "C" void kernel_launch(void* const* d_in, const int* in_sizes, int n_in,
                              void* d_out, int out_size, void* d_ws, size_t ws_size,
                              hipStream_t stream) {
    const float* y   = (const float*)d_in[0];
    const float* x   = (const float*)d_in[1];
    const float* gyw = (const float*)d_in[2];
    const float* gyb = (const float*)d_in[3];
    const float* gxw = (const float*)d_in[4];
    const float* gxb = (const float*)d_in[5];
    const float* qw  = (const float*)d_in[6];
    const float* qb  = (const float*)d_in[7];
    const float* kw  = (const float*)d_in[8];
    const float* kb  = (const float*)d_in[9];
    float* out = (float*)d_out;
    float* ws  = (float*)d_ws;

    float* part   = ws;              // 2560
    float* WeffQ  = ws + 2560;       // 32768
    float* beffQ  = ws + 35328;      // 128
    float* WeffK  = ws + 35456;      // 32768
    float* beffK  = ws + 68224;      // 128
    float* qbuf   = ws + 68352;      // 4*16384*32 = 2097152
    float* kbuf   = ws + 2165504;    // 4*4096*32  = 524288
    float* attnbf = ws + 2689792;    // 4*64*7168  = 1835008  (total ~18 MB)

    stats_kernel<<<1280, 256, 0, stream>>>(y, x, part);
    make_eff_kernel<<<256, 64, 0, stream>>>(qw, qb, gyw, gyb, kw, kb, gxw, gxb,
                                            part, WeffQ, beffQ, WeffK, beffK);
    proj_kernel<<<640, 256, 0, stream>>>(y, x, WeffQ, beffQ, WeffK, beffK, qbuf, kbuf);
    attn_weights_kernel<<<dim3(8, 8, 4), 512, 0, stream>>>(qbuf, kbuf, attnbf);
    gather_kernel<<<dim3(8, 8, 16), 256, 0, stream>>>(attnbf, x, out);
}